// Round 20
// baseline (78.342 us; speedup 1.0000x reference)
//
#include <hip/hip_runtime.h>
#include <stdint.h>
#include <stddef.h>

typedef __bf16 bf16x8 __attribute__((ext_vector_type(8)));
typedef float f32x4 __attribute__((ext_vector_type(4)));
typedef float f32x16 __attribute__((ext_vector_type(16)));
typedef int int4v __attribute__((ext_vector_type(4)));
typedef unsigned short u16;
typedef unsigned int u32;

__device__ __forceinline__ u16 f2bf(float f) {
    union { float f; unsigned u; } x; x.f = f;
    unsigned r = x.u + 0x7fffu + ((x.u >> 16) & 1u);
    return (u16)(r >> 16);
}

__device__ __forceinline__ float fexp2(float x) { return __builtin_amdgcn_exp2f(x); }

__device__ __forceinline__ u32 cvtpk(float lo, float hi) {
    u32 r;
    asm("v_cvt_pk_bf16_f32 %0, %1, %2" : "=v"(r) : "v"(lo), "v"(hi));
    return r;
}

__device__ __forceinline__ void perm32swap(u32& a, u32& b) {
    asm("v_permlane32_swap_b32 %0, %1" : "+v"(a), "+v"(b));
}

__device__ __forceinline__ f32x16 mfma32(bf16x8 a, bf16x8 b, f32x16 c) {
    return __builtin_amdgcn_mfma_f32_32x32x16_bf16(a, b, c, 0, 0, 0);
}

// async global->LDS, 16B/lane: dst wave-uniform base (+lane*16 by HW), src per-lane
__device__ __forceinline__ void gl16(const void* g, void* l) {
    __builtin_amdgcn_global_load_lds(
        (const __attribute__((address_space(1))) void*)g,
        (__attribute__((address_space(3))) void*)l, 16, 0, 0);
}

// ---------- weight transpose+pack: W[512][512] f32 -> W'[k0][n][g'] bf16 ----------
__global__ __launch_bounds__(256) void wtrans4(
        const float* __restrict__ Wq, const float* __restrict__ Wk,
        const float* __restrict__ Wv, const float* __restrict__ Wo,
        u16* __restrict__ oq, u16* __restrict__ ok,
        u16* __restrict__ ov, u16* __restrict__ oo) {
    const int z = blockIdx.z;
    const float* W = (z == 0) ? Wq : (z == 1) ? Wk : (z == 2) ? Wv : Wo;
    u16* O = (z == 0) ? oq : (z == 1) ? ok : (z == 2) ? ov : oo;
    int t  = blockIdx.x * 256 + threadIdx.x;   // 0..32767
    int g  = t >> 12;
    int k0 = (t >> 9) & 7;
    int n  = t & 511;
    float v[8];
#pragma unroll
    for (int j = 0; j < 8; ++j)
        v[j] = W[(size_t)(k0 * 64 + g * 8 + j) * 512 + n];
    int gs = g ^ (n & 7);
    u16* dst = O + ((size_t)(k0 * 512 + n) * 8 + gs) * 8;
    ushort4 a, b;
    a.x = f2bf(v[0]); a.y = f2bf(v[1]); a.z = f2bf(v[2]); a.w = f2bf(v[3]);
    b.x = f2bf(v[4]); b.y = f2bf(v[5]); b.z = f2bf(v[6]); b.w = f2bf(v[7]);
    *(ushort4*)dst = a;
    *(ushort4*)(dst + 4) = b;
}

// ---------- fused QKV GEMM: 128x256 tile, BK=64, 8 waves ----------
// grid (64, 6): y 0,1 -> Q from hidden (bcol 0/256); y 2,3 -> K-pack from enc;
// y 4,5 -> V-pack from enc. A staged 2x (hidden) / 4x (enc).
__global__ __launch_bounds__(512) void gemm_qkv(
        const float* __restrict__ hidden, const float* __restrict__ enc,
        const u16* __restrict__ wq, const u16* __restrict__ wk, const u16* __restrict__ wv,
        u16* __restrict__ qo, u16* __restrict__ ko, u16* __restrict__ vo) {
    __shared__ __align__(16) u16 As[128 * 64];
    __shared__ __align__(16) u16 Bs[256 * 64];
    const int y  = blockIdx.y;
    const int zz = (y < 2) ? 0 : (y < 4 ? 1 : 2);
    const float* A = (zz == 0) ? hidden : enc;
    const u16* Bp = (zz == 0) ? wq : (zz == 1) ? wk : wv;
    const int tid = threadIdx.x, lane = tid & 63, wave = tid >> 6;
    const int wr = (wave >> 2) * 64, wc = (wave & 3) * 64;
    const int brow = blockIdx.x * 128, bcol = (y & 1) * 256;
    const int lrow = lane & 15;

    f32x4 acc[4][4] = {};

    for (int k0s = 0; k0s < 8; ++k0s) {
        const u16* bsrc = Bp + ((size_t)(k0s * 512 + bcol) * 64) + (size_t)(wave * 256 + lane) * 8;
#pragma unroll
        for (int i = 0; i < 4; ++i)
            gl16(bsrc + i * 512, (char*)Bs + wave * 4096 + i * 1024);
#pragma unroll
        for (int i = 0; i < 2; ++i) {
            int g = i * 512 + tid;
            int r = g >> 3, gc = g & 7;
            const float* src = A + (size_t)(brow + r) * 512 + k0s * 64 + gc * 8;
            float4 f0 = *(const float4*)src, f1 = *(const float4*)(src + 4);
            int4v w;
            w[0] = cvtpk(f0.x, f0.y); w[1] = cvtpk(f0.z, f0.w);
            w[2] = cvtpk(f1.x, f1.y); w[3] = cvtpk(f1.z, f1.w);
            *(int4v*)((char*)As + r * 128 + ((gc ^ (r & 7)) << 4)) = w;
        }
        __syncthreads();
#pragma unroll
        for (int kc = 0; kc < 2; ++kc) {
            const int kg = kc * 4 + (lane >> 4);
            bf16x8 af[4], bfr[4];
#pragma unroll
            for (int m = 0; m < 4; ++m) {
                int r = wr + m * 16 + lrow;
                af[m] = *(const bf16x8*)((char*)As + r * 128 + ((kg ^ (r & 7)) << 4));
            }
#pragma unroll
            for (int n = 0; n < 4; ++n) {
                int r = wc + n * 16 + lrow;
                bfr[n] = *(const bf16x8*)((char*)Bs + r * 128 + ((kg ^ (r & 7)) << 4));
            }
#pragma unroll
            for (int m = 0; m < 4; ++m)
#pragma unroll
                for (int n = 0; n < 4; ++n)
                    acc[m][n] = __builtin_amdgcn_mfma_f32_16x16x32_bf16(af[m], bfr[n], acc[m][n], 0, 0, 0);
        }
        __syncthreads();
    }

    // epilogue: C/D layout col = lane&15, row = (lane>>4)*4 + reg
#pragma unroll
    for (int m = 0; m < 4; ++m) {
        int gr0 = brow + wr + m * 16 + ((lane >> 4) << 2);
#pragma unroll
        for (int n = 0; n < 4; ++n) {
            int gc = bcol + wc + n * 16 + lrow;
            int hh = gc >> 6, d = gc & 63;
            int b = gr0 >> 11;
            int bh2 = b * 8 + hh;
            if (zz == 0) {
                int nn = gr0 & 2047;
#pragma unroll
                for (int j = 0; j < 4; ++j)
                    qo[((size_t)bh2 * 2048 + nn + j) * 64 + d] =
                        f2bf(acc[m][n][j] * (0.125f * 1.44269504f));
            } else if (zz == 1) {
                int kc2 = d >> 4, hl2 = (d >> 3) & 1, e = d & 7;
#pragma unroll
                for (int j = 0; j < 4; ++j) {
                    int nn = (gr0 & 2047) + j;
                    size_t off = (((size_t)bh2 * 64 + (nn >> 5)) * 4 + kc2) * 512
                               + (size_t)((nn & 31) + 32 * hl2) * 8 + e;
                    ko[off] = f2bf(acc[m][n][j]);
                }
            } else {
                int nn0 = gr0 & 2047;
                int slice = ((nn0 >> 4) & 1) * 2 + (d >> 5);
                int lanev = (d & 31) + 32 * ((nn0 >> 3) & 1);
                size_t off = (((size_t)bh2 * 64 + (nn0 >> 5)) * 4 + slice) * 512
                           + (size_t)lanev * 8 + (nn0 & 7);
                ushort4 pk;
                pk.x = f2bf(acc[m][n][0]); pk.y = f2bf(acc[m][n][1]);
                pk.z = f2bf(acc[m][n][2]); pk.w = f2bf(acc[m][n][3]);
                *(ushort4*)(vo + off) = pk;
            }
        }
    }
}

// ---------- output GEMM: out = at @ Wo^T + bo; 128x128 tile, 8 waves ----------
// grid (64, 4), 512 thr: 8 waves (2x4 of 64x32). A staged 4x (was 8x).
__global__ __launch_bounds__(512) void gemm_out(
        const u16* __restrict__ A, const u16* __restrict__ Bp,
        const float* __restrict__ bias, float* __restrict__ out) {
    __shared__ __align__(16) u16 As[128 * 64];
    __shared__ __align__(16) u16 Bs[128 * 64];
    const int tid = threadIdx.x, lane = tid & 63, wave = tid >> 6;
    const int wr = (wave >> 2) * 64, wc = (wave & 3) * 32;
    const int brow = blockIdx.x * 128, bcol = blockIdx.y * 128;
    const int lrow = lane & 15;

    f32x4 acc[4][2] = {};

    for (int k0s = 0; k0s < 8; ++k0s) {
        // A: 2 gl16/thread, per-lane gathered source (image pre-swizzled), linear dst
#pragma unroll
        for (int i = 0; i < 2; ++i) {
            int r = i * 64 + wave * 8 + (lane >> 3);
            const u16* asrc = A + (size_t)(brow + r) * 512 + k0s * 64 + (lane & 7) * 8;
            gl16(asrc, (char*)As + (i * 512 + wave * 64) * 16);
        }
        // B: 2 gl16/thread, contiguous from W' image
        const u16* bsrc = Bp + ((size_t)(k0s * 512 + bcol) * 64);
#pragma unroll
        for (int i = 0; i < 2; ++i)
            gl16(bsrc + (size_t)(i * 512 + wave * 64 + lane) * 8,
                 (char*)Bs + (i * 512 + wave * 64) * 16);
        __syncthreads();
#pragma unroll
        for (int kc = 0; kc < 2; ++kc) {
            const int kg = kc * 4 + (lane >> 4);
            bf16x8 af[4], bfr[2];
#pragma unroll
            for (int m = 0; m < 4; ++m) {
                int r = wr + m * 16 + lrow;
                af[m] = *(const bf16x8*)((char*)As + r * 128 + ((kg ^ (r & 7)) << 4));
            }
#pragma unroll
            for (int n = 0; n < 2; ++n) {
                int r = wc + n * 16 + lrow;
                bfr[n] = *(const bf16x8*)((char*)Bs + r * 128 + ((kg ^ (r & 7)) << 4));
            }
#pragma unroll
            for (int m = 0; m < 4; ++m)
#pragma unroll
                for (int n = 0; n < 2; ++n)
                    acc[m][n] = __builtin_amdgcn_mfma_f32_16x16x32_bf16(af[m], bfr[n], acc[m][n], 0, 0, 0);
        }
        __syncthreads();
    }

#pragma unroll
    for (int m = 0; m < 4; ++m) {
        int gr0 = brow + wr + m * 16 + ((lane >> 4) << 2);
#pragma unroll
        for (int n = 0; n < 2; ++n) {
            int gc = bcol + wc + n * 16 + lrow;
            float bv = bias[gc];
#pragma unroll
            for (int j = 0; j < 4; ++j)
                out[(size_t)(gr0 + j) * 512 + gc] = acc[m][n][j] + bv;
        }
    }
}

// ---------- flash attention v14 (best measured): packed frag staging, 33KB LDS ----
__global__ __launch_bounds__(256, 2) void flash_attn(
        const u16* __restrict__ KQ, const u16* __restrict__ KP,
        const u16* __restrict__ VP, u16* __restrict__ Oa) {
    __shared__ __align__(16) char smem[33280];

    const int tid  = threadIdx.x;
    const int lane = tid & 63;
    const int wave = tid >> 6;
    const int qg   = wave >> 1;
    const int half = wave & 1;
    const int ql   = lane & 31;
    const int hl   = lane >> 5;
    const int bid  = blockIdx.x;
    const int lid  = (bid & 7) * 64 + (bid >> 3);
    const int bh   = lid >> 4;
    const int qt   = lid & 15;
    const int qbase = qt * 128 + qg * 64;

    bf16x8 qf[2][4];
#pragma unroll
    for (int sq = 0; sq < 2; ++sq)
#pragma unroll
        for (int kc = 0; kc < 4; ++kc)
            qf[sq][kc] = *(const bf16x8*)(KQ + ((size_t)bh * 2048 + qbase + sq * 32 + ql) * 64 + kc * 16 + hl * 8);

    const u16* Pb = (qg == 0 ? KP : VP) + ((size_t)bh * 64 + half * 32) * 2048 + lane * 8;
    char* dst0 = smem + half * 8192 + (qg == 0 ? 0 : 4096);

#define STAGE(b_, t_) do { \
    const u16* s_ = Pb + (size_t)(t_) * 2048; \
    char* d_ = dst0 + (b_) * 16384; \
    gl16(s_,        d_); \
    gl16(s_ + 512,  d_ + 1024); \
    gl16(s_ + 1024, d_ + 2048); \
    gl16(s_ + 1536, d_ + 3072); \
} while (0)

    f32x16 acc00 = {}, acc01 = {}, acc10 = {}, acc11 = {};
    float ls[2][4] = {};

    STAGE(0, 0);
    __syncthreads();

    for (int t = 0; t < 32; ++t) {
        const int b = t & 1;
        if (t < 31) STAGE(b ^ 1, t + 1);

        const u16* Kt = (const u16*)(smem + b * 16384 + half * 8192);
        const u16* Vt = Kt + 2048;
        bf16x8 kf[4], vf[2][2];
#pragma unroll
        for (int kc = 0; kc < 4; ++kc)
            kf[kc] = *(const bf16x8*)(Kt + kc * 512 + lane * 8);
#pragma unroll
        for (int jl = 0; jl < 2; ++jl)
#pragma unroll
            for (int dh2 = 0; dh2 < 2; ++dh2)
                vf[jl][dh2] = *(const bf16x8*)(Vt + (jl * 2 + dh2) * 512 + lane * 8);

        f32x16 st0 = {}, st1 = {};
        __builtin_amdgcn_s_setprio(1);
#pragma unroll
        for (int kc = 0; kc < 4; ++kc) {
            st0 = mfma32(kf[kc], qf[0][kc], st0);
            st1 = mfma32(kf[kc], qf[1][kc], st1);
        }
        __builtin_amdgcn_s_setprio(0);

#pragma unroll
        for (int r = 0; r < 16; r += 4) {
            st0[r]   = fexp2(st0[r]);   ls[0][0] += st0[r];
            st0[r+1] = fexp2(st0[r+1]); ls[0][1] += st0[r+1];
            st0[r+2] = fexp2(st0[r+2]); ls[0][2] += st0[r+2];
            st0[r+3] = fexp2(st0[r+3]); ls[0][3] += st0[r+3];
            st1[r]   = fexp2(st1[r]);   ls[1][0] += st1[r];
            st1[r+1] = fexp2(st1[r+1]); ls[1][1] += st1[r+1];
            st1[r+2] = fexp2(st1[r+2]); ls[1][2] += st1[r+2];
            st1[r+3] = fexp2(st1[r+3]); ls[1][3] += st1[r+3];
        }

        __builtin_amdgcn_s_setprio(1);
#pragma unroll
        for (int jl = 0; jl < 2; ++jl) {
            u32 A0 = cvtpk(st0[8*jl+0], st0[8*jl+1]);
            u32 A1 = cvtpk(st0[8*jl+2], st0[8*jl+3]);
            u32 B0 = cvtpk(st0[8*jl+4], st0[8*jl+5]);
            u32 B1 = cvtpk(st0[8*jl+6], st0[8*jl+7]);
            perm32swap(A0, B0);
            perm32swap(A1, B1);
            union { bf16x8 v; u32 u[4]; } bb0;
            bb0.u[0] = A0; bb0.u[1] = A1; bb0.u[2] = B0; bb0.u[3] = B1;
            acc00 = mfma32(vf[jl][0], bb0.v, acc00);
            acc01 = mfma32(vf[jl][1], bb0.v, acc01);
            u32 C0 = cvtpk(st1[8*jl+0], st1[8*jl+1]);
            u32 C1 = cvtpk(st1[8*jl+2], st1[8*jl+3]);
            u32 D0 = cvtpk(st1[8*jl+4], st1[8*jl+5]);
            u32 D1 = cvtpk(st1[8*jl+6], st1[8*jl+7]);
            perm32swap(C0, D0);
            perm32swap(C1, D1);
            union { bf16x8 v; u32 u[4]; } bb1;
            bb1.u[0] = C0; bb1.u[1] = C1; bb1.u[2] = D0; bb1.u[3] = D1;
            acc10 = mfma32(vf[jl][0], bb1.v, acc10);
            acc11 = mfma32(vf[jl][1], bb1.v, acc11);
        }
        __builtin_amdgcn_s_setprio(0);

        __syncthreads();
    }
#undef STAGE

    float lsum0 = (ls[0][0] + ls[0][1]) + (ls[0][2] + ls[0][3]);
    float lsum1 = (ls[1][0] + ls[1][1]) + (ls[1][2] + ls[1][3]);
    lsum0 += __shfl_xor(lsum0, 32);
    lsum1 += __shfl_xor(lsum1, 32);

    float* CB = (float*)smem;
    float* LS = (float*)(smem + 32768);

#define PUBQ(sq, A0, A1, LSV) do { \
    int qq = (sq) * 32 + ql; \
    float* R = CB + qg * 4096 + qq * 64; \
    _Pragma("unroll") \
    for (int rg = 0; rg < 4; ++rg) { \
        int g0 = (2 * rg + hl) ^ (qq & 15); \
        *(f32x4*)(R + g0 * 4) = f32x4{A0[4*rg], A0[4*rg+1], A0[4*rg+2], A0[4*rg+3]}; \
        int g1 = (8 + 2 * rg + hl) ^ (qq & 15); \
        *(f32x4*)(R + g1 * 4) = f32x4{A1[4*rg], A1[4*rg+1], A1[4*rg+2], A1[4*rg+3]}; \
    } \
    if (hl == 0) LS[qg * 64 + qq] = LSV; \
} while (0)

#define REDQ(sq, A0, A1, LSV) do { \
    int qq = (sq) * 32 + ql; \
    const float* R = CB + qg * 4096 + qq * 64; \
    _Pragma("unroll") \
    for (int rg = 0; rg < 4; ++rg) { \
        int g0 = (2 * rg + hl) ^ (qq & 15); \
        f32x4 v0 = *(const f32x4*)(R + g0 * 4); \
        A0[4*rg] += v0[0]; A0[4*rg+1] += v0[1]; A0[4*rg+2] += v0[2]; A0[4*rg+3] += v0[3]; \
        int g1 = (8 + 2 * rg + hl) ^ (qq & 15); \
        f32x4 v1 = *(const f32x4*)(R + g1 * 4); \
        A1[4*rg] += v1[0]; A1[4*rg+1] += v1[1]; A1[4*rg+2] += v1[2]; A1[4*rg+3] += v1[3]; \
    } \
    LSV += LS[qg * 64 + qq]; \
} while (0)

    if (half == 1) {
        PUBQ(0, acc00, acc01, lsum0);
        PUBQ(1, acc10, acc11, lsum1);
    }
    __syncthreads();
    if (half == 0) {
        REDQ(0, acc00, acc01, lsum0);
        REDQ(1, acc10, acc11, lsum1);
        float inv0 = 1.0f / lsum0, inv1 = 1.0f / lsum1;
        int b_ = bh >> 3, hd = bh & 7;
#define STOQ(sq, A0, A1, INV) do { \
        int qrow = qbase + (sq) * 32 + ql; \
        u16* orow = Oa + ((size_t)b_ * 2048 + qrow) * 512 + hd * 64; \
        _Pragma("unroll") \
        for (int rg = 0; rg < 4; ++rg) { \
            int d00 = ((rg ^ (qrow & 7)) << 3) + hl * 4; \
            ushort4 p0; \
            p0.x = f2bf(A0[4*rg] * INV);   p0.y = f2bf(A0[4*rg+1] * INV); \
            p0.z = f2bf(A0[4*rg+2] * INV); p0.w = f2bf(A0[4*rg+3] * INV); \
            *(ushort4*)(orow + d00) = p0; \
            int d01 = (((4 + rg) ^ (qrow & 7)) << 3) + hl * 4; \
            ushort4 p1; \
            p1.x = f2bf(A1[4*rg] * INV);   p1.y = f2bf(A1[4*rg+1] * INV); \
            p1.z = f2bf(A1[4*rg+2] * INV); p1.w = f2bf(A1[4*rg+3] * INV); \
            *(ushort4*)(orow + d01) = p1; \
        } \
} while (0)
        STOQ(0, acc00, acc01, inv0);
        STOQ(1, acc10, acc11, inv1);
#undef STOQ
    }
#undef PUBQ
#undef REDQ
}

extern "C" void kernel_launch(void* const* d_in, const int* in_sizes, int n_in,
                              void* d_out, int out_size, void* d_ws, size_t ws_size,
                              hipStream_t stream) {
    const float* hidden = (const float*)d_in[0];
    const float* enc    = (const float*)d_in[1];
    const float* Wq     = (const float*)d_in[2];
    const float* Wk     = (const float*)d_in[3];
    const float* Wv     = (const float*)d_in[4];
    const float* Wo     = (const float*)d_in[5];
    const float* bo     = (const float*)d_in[6];
    float* out = (float*)d_out;

    char* ws = (char*)d_ws;
    const size_t MB = 1ull << 20;
    u16* q_bf  = (u16*)(ws + 0 * MB);   // [bh][2048][64] (pre-scaled 0.125*log2e)
    u16* kp_bf = (u16*)(ws + 8 * MB);   // K frag pack [bh][64][4][64][8], 8MB
    u16* vp_bf = (u16*)(ws + 16 * MB);  // V frag pack [bh][64][4][64][8], 8MB
    u16* at_bf = (u16*)(ws + 24 * MB);  // [8192][512] pre-swizzled image
    u16* wq_t  = (u16*)(ws + 32 * MB);
    u16* wk_t  = (u16*)(ws + 32 * MB + 512 * 1024);
    u16* wv_t  = (u16*)(ws + 33 * MB);
    u16* wo_t  = (u16*)(ws + 33 * MB + 512 * 1024);

    dim3 wg(128, 1, 4);
    wtrans4<<<wg, 256, 0, stream>>>(Wq, Wk, Wv, Wo, wq_t, wk_t, wv_t, wo_t);

    dim3 qkvg(64, 6);
    gemm_qkv<<<qkvg, 512, 0, stream>>>(hidden, enc, wq_t, wk_t, wv_t, q_bf, kp_bf, vp_bf);

    flash_attn<<<512, 256, 0, stream>>>(q_bf, kp_bf, vp_bf, at_bf);

    dim3 og(64, 4);
    gemm_out<<<og, 512, 0, stream>>>(at_bf, wo_t, bo, out);
}

// Round 21
// 76.591 us; speedup vs baseline: 1.0229x; 1.0229x over previous
//
#include <hip/hip_runtime.h>
#include <stdint.h>
#include <stddef.h>

typedef __bf16 bf16x8 __attribute__((ext_vector_type(8)));
typedef float f32x4 __attribute__((ext_vector_type(4)));
typedef float f32x16 __attribute__((ext_vector_type(16)));
typedef int int4v __attribute__((ext_vector_type(4)));
typedef unsigned short u16;
typedef unsigned int u32;

__device__ __forceinline__ u16 f2bf(float f) {
    union { float f; unsigned u; } x; x.f = f;
    unsigned r = x.u + 0x7fffu + ((x.u >> 16) & 1u);
    return (u16)(r >> 16);
}

__device__ __forceinline__ float fexp2(float x) { return __builtin_amdgcn_exp2f(x); }

__device__ __forceinline__ u32 cvtpk(float lo, float hi) {
    u32 r;
    asm("v_cvt_pk_bf16_f32 %0, %1, %2" : "=v"(r) : "v"(lo), "v"(hi));
    return r;
}

__device__ __forceinline__ void perm32swap(u32& a, u32& b) {
    asm("v_permlane32_swap_b32 %0, %1" : "+v"(a), "+v"(b));
}

__device__ __forceinline__ f32x16 mfma32(bf16x8 a, bf16x8 b, f32x16 c) {
    return __builtin_amdgcn_mfma_f32_32x32x16_bf16(a, b, c, 0, 0, 0);
}

// async global->LDS, 16B/lane: dst wave-uniform base (+lane*16 by HW), src per-lane
__device__ __forceinline__ void gl16(const void* g, void* l) {
    __builtin_amdgcn_global_load_lds(
        (const __attribute__((address_space(1))) void*)g,
        (__attribute__((address_space(3))) void*)l, 16, 0, 0);
}

// ---------- weight transpose+pack: W[512][512] f32 -> W'[k0][n][g'] bf16 ----------
__global__ __launch_bounds__(256) void wtrans4(
        const float* __restrict__ Wq, const float* __restrict__ Wk,
        const float* __restrict__ Wv, const float* __restrict__ Wo,
        u16* __restrict__ oq, u16* __restrict__ ok,
        u16* __restrict__ ov, u16* __restrict__ oo) {
    const int z = blockIdx.z;
    const float* W = (z == 0) ? Wq : (z == 1) ? Wk : (z == 2) ? Wv : Wo;
    u16* O = (z == 0) ? oq : (z == 1) ? ok : (z == 2) ? ov : oo;
    int t  = blockIdx.x * 256 + threadIdx.x;   // 0..32767
    int g  = t >> 12;
    int k0 = (t >> 9) & 7;
    int n  = t & 511;
    float v[8];
#pragma unroll
    for (int j = 0; j < 8; ++j)
        v[j] = W[(size_t)(k0 * 64 + g * 8 + j) * 512 + n];
    int gs = g ^ (n & 7);
    u16* dst = O + ((size_t)(k0 * 512 + n) * 8 + gs) * 8;
    ushort4 a, b;
    a.x = f2bf(v[0]); a.y = f2bf(v[1]); a.z = f2bf(v[2]); a.w = f2bf(v[3]);
    b.x = f2bf(v[4]); b.y = f2bf(v[5]); b.z = f2bf(v[6]); b.w = f2bf(v[7]);
    *(ushort4*)dst = a;
    *(ushort4*)(dst + 4) = b;
}

// ---------- fused QKV GEMM: 128x256 tile, BK=64, 8 waves ----------
// grid (64, 6): y 0,1 -> Q from hidden (bcol 0/256); y 2,3 -> K-pack from enc;
// y 4,5 -> V-pack from enc. A staged 2x (hidden) / 4x (enc) instead of 4x/8x.
// Packs: [bh][chunk=kv>>5][slice 0..3][lane 0..63][8] (flash's LDS slice image).
__global__ __launch_bounds__(512) void gemm_qkv(
        const float* __restrict__ hidden, const float* __restrict__ enc,
        const u16* __restrict__ wq, const u16* __restrict__ wk, const u16* __restrict__ wv,
        u16* __restrict__ qo, u16* __restrict__ ko, u16* __restrict__ vo) {
    __shared__ __align__(16) u16 As[128 * 64];
    __shared__ __align__(16) u16 Bs[256 * 64];
    const int y  = blockIdx.y;
    const int zz = (y < 2) ? 0 : (y < 4 ? 1 : 2);
    const float* A = (zz == 0) ? hidden : enc;
    const u16* Bp = (zz == 0) ? wq : (zz == 1) ? wk : wv;
    const int tid = threadIdx.x, lane = tid & 63, wave = tid >> 6;
    const int wr = (wave >> 2) * 64, wc = (wave & 3) * 64;
    const int brow = blockIdx.x * 128, bcol = (y & 1) * 256;
    const int lrow = lane & 15;

    f32x4 acc[4][4] = {};

    for (int k0s = 0; k0s < 8; ++k0s) {
        // B: 32KB pre-swizzled image, 4 gl16/wave, contiguous source
        const u16* bsrc = Bp + ((size_t)(k0s * 512 + bcol) * 64) + (size_t)(wave * 256 + lane) * 8;
#pragma unroll
        for (int i = 0; i < 4; ++i)
            gl16(bsrc + i * 512, (char*)Bs + wave * 4096 + i * 1024);
        // A: f32 -> bf16 staged, 2 granules/thread
#pragma unroll
        for (int i = 0; i < 2; ++i) {
            int g = i * 512 + tid;
            int r = g >> 3, gc = g & 7;
            const float* src = A + (size_t)(brow + r) * 512 + k0s * 64 + gc * 8;
            float4 f0 = *(const float4*)src, f1 = *(const float4*)(src + 4);
            int4v w;
            w[0] = cvtpk(f0.x, f0.y); w[1] = cvtpk(f0.z, f0.w);
            w[2] = cvtpk(f1.x, f1.y); w[3] = cvtpk(f1.z, f1.w);
            *(int4v*)((char*)As + r * 128 + ((gc ^ (r & 7)) << 4)) = w;
        }
        __syncthreads();
#pragma unroll
        for (int kc = 0; kc < 2; ++kc) {
            const int kg = kc * 4 + (lane >> 4);
            bf16x8 af[4], bfr[4];
#pragma unroll
            for (int m = 0; m < 4; ++m) {
                int r = wr + m * 16 + lrow;
                af[m] = *(const bf16x8*)((char*)As + r * 128 + ((kg ^ (r & 7)) << 4));
            }
#pragma unroll
            for (int n = 0; n < 4; ++n) {
                int r = wc + n * 16 + lrow;
                bfr[n] = *(const bf16x8*)((char*)Bs + r * 128 + ((kg ^ (r & 7)) << 4));
            }
#pragma unroll
            for (int m = 0; m < 4; ++m)
#pragma unroll
                for (int n = 0; n < 4; ++n)
                    acc[m][n] = __builtin_amdgcn_mfma_f32_16x16x32_bf16(af[m], bfr[n], acc[m][n], 0, 0, 0);
        }
        __syncthreads();
    }

    // epilogue: C/D layout col = lane&15, row = (lane>>4)*4 + reg
#pragma unroll
    for (int m = 0; m < 4; ++m) {
        int gr0 = brow + wr + m * 16 + ((lane >> 4) << 2);
#pragma unroll
        for (int n = 0; n < 4; ++n) {
            int gc = bcol + wc + n * 16 + lrow;
            int hh = gc >> 6, d = gc & 63;
            int b = gr0 >> 11;
            int bh2 = b * 8 + hh;
            if (zz == 0) {
                int nn = gr0 & 2047;
#pragma unroll
                for (int j = 0; j < 4; ++j)
                    qo[((size_t)bh2 * 2048 + nn + j) * 64 + d] =
                        f2bf(acc[m][n][j] * (0.125f * 1.44269504f));
            } else if (zz == 1) {
                // K pack: slice = kc = d>>4; lane = (kv&31) + 32*((d>>3)&1); e = d&7
                int kc2 = d >> 4, hl2 = (d >> 3) & 1, e = d & 7;
#pragma unroll
                for (int j = 0; j < 4; ++j) {
                    int nn = (gr0 & 2047) + j;
                    size_t off = (((size_t)bh2 * 64 + (nn >> 5)) * 4 + kc2) * 512
                               + (size_t)((nn & 31) + 32 * hl2) * 8 + e;
                    ko[off] = f2bf(acc[m][n][j]);
                }
            } else {
                // V pack: slice = ((kv>>4)&1)*2 + (d>>5); lane = (d&31) + 32*((kv>>3)&1); e = kv&7
                int nn0 = gr0 & 2047;
                int slice = ((nn0 >> 4) & 1) * 2 + (d >> 5);
                int lanev = (d & 31) + 32 * ((nn0 >> 3) & 1);
                size_t off = (((size_t)bh2 * 64 + (nn0 >> 5)) * 4 + slice) * 512
                           + (size_t)lanev * 8 + (nn0 & 7);
                ushort4 pk;
                pk.x = f2bf(acc[m][n][0]); pk.y = f2bf(acc[m][n][1]);
                pk.z = f2bf(acc[m][n][2]); pk.w = f2bf(acc[m][n][3]);
                *(ushort4*)(vo + off) = pk;
            }
        }
    }
}

// ---------- output GEMM: out = at @ Wo^T + bo; 128x64 tile ----------
__global__ __launch_bounds__(256) void gemm_out(
        const u16* __restrict__ A, const u16* __restrict__ Bp,
        const float* __restrict__ bias, float* __restrict__ out) {
    __shared__ __align__(16) u16 As[128 * 64];
    __shared__ __align__(16) u16 Bs[64 * 64];
    const int tid = threadIdx.x, lane = tid & 63, wave = tid >> 6;
    const int wr = (wave >> 1) * 64, wc = (wave & 1) * 32;
    const int brow = blockIdx.x * 128, bcol = blockIdx.y * 64;
    const int lrow = lane & 15;
    const int ar = wave * 32 + (lane >> 3), ag = lane & 7;

    f32x4 acc[4][2] = {};

    for (int k0s = 0; k0s < 8; ++k0s) {
        const u16* asrc = A + (size_t)(brow + ar) * 512 + k0s * 64 + ag * 8;
#pragma unroll
        for (int i = 0; i < 4; ++i)
            gl16(asrc + (size_t)(i * 8) * 512, (char*)As + wave * 4096 + i * 1024);
        const u16* bsrc = Bp + ((size_t)(k0s * 512 + bcol) * 64) + (size_t)(wave * 128 + lane) * 8;
#pragma unroll
        for (int i = 0; i < 2; ++i)
            gl16(bsrc + i * 512, (char*)Bs + wave * 2048 + i * 1024);
        __syncthreads();
#pragma unroll
        for (int kc = 0; kc < 2; ++kc) {
            const int kg = kc * 4 + (lane >> 4);
            bf16x8 af[4], bfr[2];
#pragma unroll
            for (int m = 0; m < 4; ++m) {
                int r = wr + m * 16 + lrow;
                af[m] = *(const bf16x8*)((char*)As + r * 128 + ((kg ^ (r & 7)) << 4));
            }
#pragma unroll
            for (int n = 0; n < 2; ++n) {
                int r = wc + n * 16 + lrow;
                bfr[n] = *(const bf16x8*)((char*)Bs + r * 128 + ((kg ^ (r & 7)) << 4));
            }
#pragma unroll
            for (int m = 0; m < 4; ++m)
#pragma unroll
                for (int n = 0; n < 2; ++n)
                    acc[m][n] = __builtin_amdgcn_mfma_f32_16x16x32_bf16(af[m], bfr[n], acc[m][n], 0, 0, 0);
        }
        __syncthreads();
    }

#pragma unroll
    for (int m = 0; m < 4; ++m) {
        int gr0 = brow + wr + m * 16 + ((lane >> 4) << 2);
#pragma unroll
        for (int n = 0; n < 2; ++n) {
            int gc = bcol + wc + n * 16 + lrow;
            float bv = bias[gc];
#pragma unroll
            for (int j = 0; j < 4; ++j)
                out[(size_t)(gr0 + j) * 512 + gc] = acc[m][n][j] + bv;
        }
    }
}

// ---------- flash attention v14 (best measured): packed frag staging, 33KB LDS ----
// 512 blocks x 256 thr (4 waves = 2 qgroups-of-64 x 2 kv-halves of 1024).
// Per step (32 kv per half): stage K 4KB + V 4KB from packed global (contiguous
// 1KB/gl16), read back as contiguous slice+lane*16 ds_read_b128 (0 conflicts).
// qg0 wave stages K for its half, qg1 stages V. One barrier/step, dbuf.
// (256,2): register allocator free (88 VGPR measured, no spill).
__global__ __launch_bounds__(256, 2) void flash_attn(
        const u16* __restrict__ KQ, const u16* __restrict__ KP,
        const u16* __restrict__ VP, u16* __restrict__ Oa) {
    __shared__ __align__(16) char smem[33280];  // [2 buf][2 half][K 4KB | V 4KB]; combine reuse

    const int tid  = threadIdx.x;
    const int lane = tid & 63;
    const int wave = tid >> 6;          // 0..3
    const int qg   = wave >> 1;         // qgroup of 64
    const int half = wave & 1;          // kv half
    const int ql   = lane & 31;
    const int hl   = lane >> 5;
    const int bid  = blockIdx.x;
    const int lid  = (bid & 7) * 64 + (bid >> 3);   // bijective XCD swizzle (512=8*64)
    const int bh   = lid >> 4;
    const int qt   = lid & 15;
    const int qbase = qt * 128 + qg * 64;

    // Q b-frags for 2 sub-qgroups (pre-scaled by 0.125*log2e in gemm_qkv)
    bf16x8 qf[2][4];
#pragma unroll
    for (int sq = 0; sq < 2; ++sq)
#pragma unroll
        for (int kc = 0; kc < 4; ++kc)
            qf[sq][kc] = *(const bf16x8*)(KQ + ((size_t)bh * 2048 + qbase + sq * 32 + ql) * 64 + kc * 16 + hl * 8);

    // staging: wave's role by qg (K or V pack), its half's chunks; contiguous source
    const u16* Pb = (qg == 0 ? KP : VP) + ((size_t)bh * 64 + half * 32) * 2048 + lane * 8;
    char* dst0 = smem + half * 8192 + (qg == 0 ? 0 : 4096);

#define STAGE(b_, t_) do { \
    const u16* s_ = Pb + (size_t)(t_) * 2048; \
    char* d_ = dst0 + (b_) * 16384; \
    gl16(s_,        d_); \
    gl16(s_ + 512,  d_ + 1024); \
    gl16(s_ + 1024, d_ + 2048); \
    gl16(s_ + 1536, d_ + 3072); \
} while (0)

    f32x16 acc00 = {}, acc01 = {}, acc10 = {}, acc11 = {};
    float ls[2][4] = {};

    STAGE(0, 0);
    __syncthreads();

    for (int t = 0; t < 32; ++t) {
        const int b = t & 1;
        if (t < 31) STAGE(b ^ 1, t + 1);

        const u16* Kt = (const u16*)(smem + b * 16384 + half * 8192);
        const u16* Vt = Kt + 2048;
        bf16x8 kf[4], vf[2][2];
#pragma unroll
        for (int kc = 0; kc < 4; ++kc)
            kf[kc] = *(const bf16x8*)(Kt + kc * 512 + lane * 8);
#pragma unroll
        for (int jl = 0; jl < 2; ++jl)
#pragma unroll
            for (int dh2 = 0; dh2 < 2; ++dh2)
                vf[jl][dh2] = *(const bf16x8*)(Vt + (jl * 2 + dh2) * 512 + lane * 8);

        // ST = K . Q^T for both sub-qgroups
        f32x16 st0 = {}, st1 = {};
        __builtin_amdgcn_s_setprio(1);
#pragma unroll
        for (int kc = 0; kc < 4; ++kc) {
            st0 = mfma32(kf[kc], qf[0][kc], st0);
            st1 = mfma32(kf[kc], qf[1][kc], st1);
        }
        __builtin_amdgcn_s_setprio(0);

        // p = exp2(st); running row-sums
#pragma unroll
        for (int r = 0; r < 16; r += 4) {
            st0[r]   = fexp2(st0[r]);   ls[0][0] += st0[r];
            st0[r+1] = fexp2(st0[r+1]); ls[0][1] += st0[r+1];
            st0[r+2] = fexp2(st0[r+2]); ls[0][2] += st0[r+2];
            st0[r+3] = fexp2(st0[r+3]); ls[0][3] += st0[r+3];
            st1[r]   = fexp2(st1[r]);   ls[1][0] += st1[r];
            st1[r+1] = fexp2(st1[r+1]); ls[1][1] += st1[r+1];
            st1[r+2] = fexp2(st1[r+2]); ls[1][2] += st1[r+2];
            st1[r+3] = fexp2(st1[r+3]); ls[1][3] += st1[r+3];
        }

        // O^T += VT . P^T for both sub-qgroups
        __builtin_amdgcn_s_setprio(1);
#pragma unroll
        for (int jl = 0; jl < 2; ++jl) {
            u32 A0 = cvtpk(st0[8*jl+0], st0[8*jl+1]);
            u32 A1 = cvtpk(st0[8*jl+2], st0[8*jl+3]);
            u32 B0 = cvtpk(st0[8*jl+4], st0[8*jl+5]);
            u32 B1 = cvtpk(st0[8*jl+6], st0[8*jl+7]);
            perm32swap(A0, B0);
            perm32swap(A1, B1);
            union { bf16x8 v; u32 u[4]; } bb0;
            bb0.u[0] = A0; bb0.u[1] = A1; bb0.u[2] = B0; bb0.u[3] = B1;
            acc00 = mfma32(vf[jl][0], bb0.v, acc00);
            acc01 = mfma32(vf[jl][1], bb0.v, acc01);
            u32 C0 = cvtpk(st1[8*jl+0], st1[8*jl+1]);
            u32 C1 = cvtpk(st1[8*jl+2], st1[8*jl+3]);
            u32 D0 = cvtpk(st1[8*jl+4], st1[8*jl+5]);
            u32 D1 = cvtpk(st1[8*jl+6], st1[8*jl+7]);
            perm32swap(C0, D0);
            perm32swap(C1, D1);
            union { bf16x8 v; u32 u[4]; } bb1;
            bb1.u[0] = C0; bb1.u[1] = C1; bb1.u[2] = D0; bb1.u[3] = D1;
            acc10 = mfma32(vf[jl][0], bb1.v, acc10);
            acc11 = mfma32(vf[jl][1], bb1.v, acc11);
        }
        __builtin_amdgcn_s_setprio(0);

        __syncthreads();
    }
#undef STAGE

    float lsum0 = (ls[0][0] + ls[0][1]) + (ls[0][2] + ls[0][3]);
    float lsum1 = (ls[1][0] + ls[1][1]) + (ls[1][2] + ls[1][3]);
    lsum0 += __shfl_xor(lsum0, 32);
    lsum1 += __shfl_xor(lsum1, 32);

    // split-2 exact combine through LDS (reuse smem): region per qgroup = 16KB
    float* CB = (float*)smem;              // [qg][64 q][64 d] with granule-4 XOR
    float* LS = (float*)(smem + 32768);    // [qg][64]

#define PUBQ(sq, A0, A1, LSV) do { \
    int qq = (sq) * 32 + ql; \
    float* R = CB + qg * 4096 + qq * 64; \
    _Pragma("unroll") \
    for (int rg = 0; rg < 4; ++rg) { \
        int g0 = (2 * rg + hl) ^ (qq & 15); \
        *(f32x4*)(R + g0 * 4) = f32x4{A0[4*rg], A0[4*rg+1], A0[4*rg+2], A0[4*rg+3]}; \
        int g1 = (8 + 2 * rg + hl) ^ (qq & 15); \
        *(f32x4*)(R + g1 * 4) = f32x4{A1[4*rg], A1[4*rg+1], A1[4*rg+2], A1[4*rg+3]}; \
    } \
    if (hl == 0) LS[qg * 64 + qq] = LSV; \
} while (0)

#define REDQ(sq, A0, A1, LSV) do { \
    int qq = (sq) * 32 + ql; \
    const float* R = CB + qg * 4096 + qq * 64; \
    _Pragma("unroll") \
    for (int rg = 0; rg < 4; ++rg) { \
        int g0 = (2 * rg + hl) ^ (qq & 15); \
        f32x4 v0 = *(const f32x4*)(R + g0 * 4); \
        A0[4*rg] += v0[0]; A0[4*rg+1] += v0[1]; A0[4*rg+2] += v0[2]; A0[4*rg+3] += v0[3]; \
        int g1 = (8 + 2 * rg + hl) ^ (qq & 15); \
        f32x4 v1 = *(const f32x4*)(R + g1 * 4); \
        A1[4*rg] += v1[0]; A1[4*rg+1] += v1[1]; A1[4*rg+2] += v1[2]; A1[4*rg+3] += v1[3]; \
    } \
    LSV += LS[qg * 64 + qq]; \
} while (0)

    if (half == 1) {
        PUBQ(0, acc00, acc01, lsum0);
        PUBQ(1, acc10, acc11, lsum1);
    }
    __syncthreads();
    if (half == 0) {
        REDQ(0, acc00, acc01, lsum0);
        REDQ(1, acc10, acc11, lsum1);
        float inv0 = 1.0f / lsum0, inv1 = 1.0f / lsum1;
        int b_ = bh >> 3, hd = bh & 7;
#define STOQ(sq, A0, A1, INV) do { \
        int qrow = qbase + (sq) * 32 + ql; \
        u16* orow = Oa + ((size_t)b_ * 2048 + qrow) * 512 + hd * 64; \
        _Pragma("unroll") \
        for (int rg = 0; rg < 4; ++rg) { \
            int d00 = ((rg ^ (qrow & 7)) << 3) + hl * 4; \
            ushort4 p0; \
            p0.x = f2bf(A0[4*rg] * INV);   p0.y = f2bf(A0[4*rg+1] * INV); \
            p0.z = f2bf(A0[4*rg+2] * INV); p0.w = f2bf(A0[4*rg+3] * INV); \
            *(ushort4*)(orow + d00) = p0; \
            int d01 = (((4 + rg) ^ (qrow & 7)) << 3) + hl * 4; \
            ushort4 p1; \
            p1.x = f2bf(A1[4*rg] * INV);   p1.y = f2bf(A1[4*rg+1] * INV); \
            p1.z = f2bf(A1[4*rg+2] * INV); p1.w = f2bf(A1[4*rg+3] * INV); \
            *(ushort4*)(orow + d01) = p1; \
        } \
} while (0)
        STOQ(0, acc00, acc01, inv0);
        STOQ(1, acc10, acc11, inv1);
#undef STOQ
    }
#undef PUBQ
#undef REDQ
}

extern "C" void kernel_launch(void* const* d_in, const int* in_sizes, int n_in,
                              void* d_out, int out_size, void* d_ws, size_t ws_size,
                              hipStream_t stream) {
    const float* hidden = (const float*)d_in[0];
    const float* enc    = (const float*)d_in[1];
    const float* Wq     = (const float*)d_in[2];
    const float* Wk     = (const float*)d_in[3];
    const float* Wv     = (const float*)d_in[4];
    const float* Wo     = (const float*)d_in[5];
    const float* bo     = (const float*)d_in[6];
    float* out = (float*)d_out;

    char* ws = (char*)d_ws;
    const size_t MB = 1ull << 20;
    u16* q_bf  = (u16*)(ws + 0 * MB);   // [bh][2048][64] (pre-scaled 0.125*log2e)
    u16* kp_bf = (u16*)(ws + 8 * MB);   // K frag pack [bh][64][4][64][8], 8MB
    u16* vp_bf = (u16*)(ws + 16 * MB);  // V frag pack [bh][64][4][64][8], 8MB
    u16* at_bf = (u16*)(ws + 24 * MB);  // [8192][512] pre-swizzled image
    u16* wq_t  = (u16*)(ws + 32 * MB);
    u16* wk_t  = (u16*)(ws + 32 * MB + 512 * 1024);
    u16* wv_t  = (u16*)(ws + 33 * MB);
    u16* wo_t  = (u16*)(ws + 33 * MB + 512 * 1024);

    dim3 wg(128, 1, 4);
    wtrans4<<<wg, 256, 0, stream>>>(Wq, Wk, Wv, Wo, wq_t, wk_t, wv_t, wo_t);

    dim3 qkvg(64, 6);
    gemm_qkv<<<qkvg, 512, 0, stream>>>(hidden, enc, wq_t, wk_t, wv_t, q_bf, kp_bf, vp_bf);

    flash_attn<<<512, 256, 0, stream>>>(q_bf, kp_bf, vp_bf, at_bf);

    dim3 og(64, 8);
    gemm_out<<<og, 256, 0, stream>>>(at_bf, wo_t, bo, out);
}